// Round 1
// baseline (604.462 us; speedup 1.0000x reference)
//
#include <hip/hip_runtime.h>
#include <hip/hip_bf16.h>

// GCN encoder: z = relu(A @ relu(A @ (x@W1) + b1) @ W2 + b2)
// Strategy: bf16 MFMA GEMMs (tolerance is bf16-class), CSR-gather SpMM (no float atomics).

typedef __attribute__((ext_vector_type(8))) short bf16x8;   // 8 bf16 = 4 VGPRs (guide §3)
typedef __attribute__((ext_vector_type(4))) float f32x4;

#define NN 50000
#define NE 800000
#define NF 512
#define NH 256
#define NL 128

static __device__ __forceinline__ unsigned short f2bf(float f) {
  union { float f; unsigned int u; } v; v.f = f;
  unsigned int r = v.u + 0x7fffu + ((v.u >> 16) & 1u);   // RNE
  return (unsigned short)(r >> 16);
}

// ---------------- CSR build ----------------
extern "C" __global__ void k_hist(const int* __restrict__ rows, int* __restrict__ counts, int n) {
  int i = blockIdx.x * 256 + threadIdx.x;
  if (i < n) atomicAdd(&counts[rows[i]], 1);
}

// single-block chunked exclusive scan: each thread owns `per` consecutive bins.
extern "C" __global__ __launch_bounds__(1024) void k_scan(const int* __restrict__ counts,
    int* __restrict__ rp, int* __restrict__ cur, int n, int per) {
  __shared__ int sums[1024];
  int t = threadIdx.x;
  int start = t * per;
  int s = 0;
  for (int i = 0; i < per; ++i) { int idx = start + i; if (idx < n) s += counts[idx]; }
  sums[t] = s;
  __syncthreads();
  for (int off = 1; off < 1024; off <<= 1) {
    int v = (t >= off) ? sums[t - off] : 0;
    __syncthreads();
    sums[t] += v;
    __syncthreads();
  }
  int run = sums[t] - s;  // exclusive prefix of this thread's chunk
  for (int i = 0; i < per; ++i) {
    int idx = start + i;
    if (idx < n) { rp[idx] = run; cur[idx] = run; run += counts[idx]; }
  }
  if (t == 1023) rp[n] = sums[1023];
}

extern "C" __global__ void k_scatter(const int* __restrict__ rows, const int* __restrict__ cols,
    const float* __restrict__ vals, int* __restrict__ cur,
    int* __restrict__ scol, float* __restrict__ sval, int n) {
  int i = blockIdx.x * 256 + threadIdx.x;
  if (i < n) {
    int p = atomicAdd(&cur[rows[i]], 1);
    scol[p] = cols[i];
    sval[p] = vals[i];
  }
}

// ---------------- casts ----------------
extern "C" __global__ void k_cast4(const float4* __restrict__ in, ushort4* __restrict__ out, int n4) {
  int i = blockIdx.x * 256 + threadIdx.x;
  if (i < n4) {
    float4 f = in[i];
    ushort4 o; o.x = f2bf(f.x); o.y = f2bf(f.y); o.z = f2bf(f.z); o.w = f2bf(f.w);
    out[i] = o;
  }
}

// W [K][N] row-major (fp32) -> WT [N][K] bf16 (so GEMM B-operand stages like A)
extern "C" __global__ void k_transcast(const float* __restrict__ w, unsigned short* __restrict__ wt,
                                       int K, int N) {
  int k = blockIdx.x; int n = threadIdx.x;
  wt[(size_t)n * K + k] = f2bf(w[(size_t)k * N + n]);
}

// ---------------- bf16 MFMA GEMM: C[M][N] = A[M][K] * BT[N][K]^T ----------------
#define BM 128
#define BN 128
#define BK 32

extern "C" __global__ __launch_bounds__(256) void k_gemm(
    const unsigned short* __restrict__ A, const unsigned short* __restrict__ BT,
    float* __restrict__ C, int M, int N, int K) {
  __shared__ __align__(16) unsigned short sA[BM * BK];
  __shared__ __align__(16) unsigned short sB[BN * BK];
  int tid = threadIdx.x;
  int lane = tid & 63, wid = tid >> 6;
  int wm = (wid >> 1) * 64, wn = (wid & 1) * 64;   // 2x2 waves, 64x64 each
  int bm = blockIdx.x * BM, bn = blockIdx.y * BN;
  int l15 = lane & 15, lq = lane >> 4;
  f32x4 acc[4][4];
#pragma unroll
  for (int i = 0; i < 4; ++i)
#pragma unroll
    for (int j = 0; j < 4; ++j) acc[i][j] = (f32x4){0.f, 0.f, 0.f, 0.f};

  for (int k0 = 0; k0 < K; k0 += BK) {
    // stage: 128 rows x 32 bf16 = 8KB each; 512 x 16B units / 256 threads = 2 per side
#pragma unroll
    for (int i = 0; i < 2; ++i) {
      int u = tid + 256 * i;
      int row = u >> 2, uc = (u & 3) * 8;
      int ga = bm + row; if (ga >= M) ga = M - 1;           // clamp, discarded at store
      *(float4*)(&sA[row * BK + uc]) = *(const float4*)(A + (size_t)ga * K + k0 + uc);
      int gb = bn + row; if (gb >= N) gb = N - 1;
      *(float4*)(&sB[row * BK + uc]) = *(const float4*)(BT + (size_t)gb * K + k0 + uc);
    }
    __syncthreads();
    bf16x8 af[4], bfr[4];
#pragma unroll
    for (int t = 0; t < 4; ++t) {
      // A frag: A[m = lane&15][k = (lane>>4)*8 + j]  (guide §3, m120-verified)
      af[t]  = *(const bf16x8*)(&sA[(wm + t * 16 + l15) * BK + lq * 8]);
      bfr[t] = *(const bf16x8*)(&sB[(wn + t * 16 + l15) * BK + lq * 8]);
    }
#pragma unroll
    for (int mt = 0; mt < 4; ++mt)
#pragma unroll
      for (int nt = 0; nt < 4; ++nt)
        acc[mt][nt] = __builtin_amdgcn_mfma_f32_16x16x32_bf16(af[mt], bfr[nt], acc[mt][nt], 0, 0, 0);
    __syncthreads();
  }
  // C/D layout: col = lane&15, row = (lane>>4)*4 + reg (m89-verified)
#pragma unroll
  for (int mt = 0; mt < 4; ++mt) {
#pragma unroll
    for (int r = 0; r < 4; ++r) {
      int gr = bm + wm + mt * 16 + lq * 4 + r;
      if (gr < M) {
#pragma unroll
        for (int nt = 0; nt < 4; ++nt) {
          int gc = bn + wn + nt * 16 + l15;
          C[(size_t)gr * N + gc] = acc[mt][nt][r];
        }
      }
    }
  }
}

// ---------------- SpMM (CSR row-gather), fused bias+relu ----------------
// one wave per row, 256 feats: lane owns float4
extern "C" __global__ __launch_bounds__(256) void k_spmm256(
    const int* __restrict__ rp, const int* __restrict__ scol, const float* __restrict__ sval,
    const float* __restrict__ src, const float* __restrict__ bias,
    ushort4* __restrict__ out) {
  int row = blockIdx.x * 4 + (threadIdx.x >> 6);
  int lane = threadIdx.x & 63;
  if (row >= NN) return;
  int e0 = __builtin_amdgcn_readfirstlane(rp[row]);
  int e1 = __builtin_amdgcn_readfirstlane(rp[row + 1]);
  const float4* srcv = (const float4*)src;
  float4 acc = {0.f, 0.f, 0.f, 0.f};
  for (int e = e0; e < e1; ++e) {
    int c = scol[e];
    float v = sval[e];
    float4 g = srcv[(size_t)c * (NH / 4) + lane];
    acc.x = fmaf(v, g.x, acc.x);
    acc.y = fmaf(v, g.y, acc.y);
    acc.z = fmaf(v, g.z, acc.z);
    acc.w = fmaf(v, g.w, acc.w);
  }
  float4 b = ((const float4*)bias)[lane];
  ushort4 o;
  o.x = f2bf(fmaxf(acc.x + b.x, 0.f));
  o.y = f2bf(fmaxf(acc.y + b.y, 0.f));
  o.z = f2bf(fmaxf(acc.z + b.z, 0.f));
  o.w = f2bf(fmaxf(acc.w + b.w, 0.f));
  out[(size_t)row * (NH / 4) + lane] = o;
}

// one wave per row, 128 feats: lane owns float2; fp32 out (final output)
extern "C" __global__ __launch_bounds__(256) void k_spmm128(
    const int* __restrict__ rp, const int* __restrict__ scol, const float* __restrict__ sval,
    const float* __restrict__ src, const float* __restrict__ bias,
    float2* __restrict__ out) {
  int row = blockIdx.x * 4 + (threadIdx.x >> 6);
  int lane = threadIdx.x & 63;
  if (row >= NN) return;
  int e0 = __builtin_amdgcn_readfirstlane(rp[row]);
  int e1 = __builtin_amdgcn_readfirstlane(rp[row + 1]);
  const float2* srcv = (const float2*)src;
  float2 acc = {0.f, 0.f};
  for (int e = e0; e < e1; ++e) {
    int c = scol[e];
    float v = sval[e];
    float2 g = srcv[(size_t)c * (NL / 2) + lane];
    acc.x = fmaf(v, g.x, acc.x);
    acc.y = fmaf(v, g.y, acc.y);
  }
  float2 b = ((const float2*)bias)[lane];
  float2 o;
  o.x = fmaxf(acc.x + b.x, 0.f);
  o.y = fmaxf(acc.y + b.y, 0.f);
  out[(size_t)row * (NL / 2) + lane] = o;
}

// ---------------- launch ----------------
extern "C" void kernel_launch(void* const* d_in, const int* in_sizes, int n_in,
                              void* d_out, int out_size, void* d_ws, size_t ws_size,
                              hipStream_t stream) {
  const float* x   = (const float*)d_in[0];
  const int* erow  = (const int*)d_in[1];
  const int* ecol  = (const int*)d_in[2];
  const float* ev  = (const float*)d_in[3];
  const float* W1  = (const float*)d_in[4];
  const float* b1  = (const float*)d_in[5];
  const float* W2  = (const float*)d_in[6];
  const float* b2  = (const float*)d_in[7];

  char* ws = (char*)d_ws;
  // layout (bytes):
  unsigned short* xbf = (unsigned short*)(ws + 0);           // 51,200,000  (x as bf16)
  float* xw  = (float*)(ws + 51200000);                      // 51,200,000  (x@W1 fp32)
  unsigned short* hbf = (unsigned short*)(ws + 102400000);   // 25,600,000  (h as bf16)
  float* hw  = (float*)(ws + 0);                             // 25,600,000  (h@W2, reuses xbf - dead)
  unsigned short* w1t = (unsigned short*)(ws + 128000000);   // 262,144
  unsigned short* w2t = (unsigned short*)(ws + 128262144);   // 65,536
  int* rp    = (int*)(ws + 128327680);                       // 200,704
  int* cur   = (int*)(ws + 128528384);                       // 200,704
  int* cnt   = (int*)(ws + 128729088);                       // 200,704
  int* scol  = (int*)(ws + 128929792);                       // 3,200,000
  float* sval = (float*)(ws + 132129792);                    // 3,200,000  -> end ~135.3MB

  // CSR build (shared by both SpMMs)
  hipMemsetAsync(cnt, 0, NN * sizeof(int), stream);
  k_hist<<<NE / 256, 256, 0, stream>>>(erow, cnt, NE);
  k_scan<<<1, 1024, 0, stream>>>(cnt, rp, cur, NN, (NN + 1023) / 1024);
  k_scatter<<<NE / 256, 256, 0, stream>>>(erow, ecol, ev, cur, scol, sval, NE);

  // layer 1
  k_cast4<<<(NN * NF / 4) / 256, 256, 0, stream>>>((const float4*)x, (ushort4*)xbf, NN * NF / 4);
  k_transcast<<<NF, NH, 0, stream>>>(W1, w1t, NF, NH);
  k_gemm<<<dim3((NN + BM - 1) / BM, NH / BN), 256, 0, stream>>>(xbf, w1t, xw, NN, NH, NF);
  k_spmm256<<<NN / 4, 256, 0, stream>>>(rp, scol, sval, xw, b1, (ushort4*)hbf);

  // layer 2
  k_transcast<<<NH, NL, 0, stream>>>(W2, w2t, NH, NL);
  k_gemm<<<dim3((NN + BM - 1) / BM, NL / BN), 256, 0, stream>>>(hbf, w2t, hw, NN, NL, NH);
  k_spmm128<<<NN / 4, 256, 0, stream>>>(rp, scol, sval, hw, b2, (float2*)d_out);
}

// Round 2
// 489.654 us; speedup vs baseline: 1.2345x; 1.2345x over previous
//
#include <hip/hip_runtime.h>
#include <hip/hip_bf16.h>

// GCN encoder: z = relu(A @ relu(A @ (x@W1) + b1) @ W2 + b2)
// bf16 MFMA GEMMs + CSR-gather SpMM. R2: hierarchical scan (R1's single-block
// k_scan was 125us latency-bound on one CU).

typedef __attribute__((ext_vector_type(8))) short bf16x8;
typedef __attribute__((ext_vector_type(4))) float f32x4;

#define NN 50000
#define NE 800000
#define NF 512
#define NH 256
#define NL 128
#define NB ((NN + 255) / 256)   // 196 scan blocks

static __device__ __forceinline__ unsigned short f2bf(float f) {
  union { float f; unsigned int u; } v; v.f = f;
  unsigned int r = v.u + 0x7fffu + ((v.u >> 16) & 1u);   // RNE
  return (unsigned short)(r >> 16);
}

// ---------------- CSR build ----------------
extern "C" __global__ void k_hist(const int* __restrict__ rows, int* __restrict__ counts, int n) {
  int i = blockIdx.x * 256 + threadIdx.x;
  if (i < n) atomicAdd(&counts[rows[i]], 1);
}

// phase 1: per-block sum of 256 counts
extern "C" __global__ __launch_bounds__(256) void k_blocksum(
    const int* __restrict__ counts, int* __restrict__ bsum, int n) {
  __shared__ int s[256];
  int t = threadIdx.x;
  int i = blockIdx.x * 256 + t;
  s[t] = (i < n) ? counts[i] : 0;
  __syncthreads();
  for (int off = 128; off > 0; off >>= 1) {
    if (t < off) s[t] += s[t + off];
    __syncthreads();
  }
  if (t == 0) bsum[blockIdx.x] = s[0];
}

// phase 2: single small block scans the NB block sums (exclusive), writes total to rp[n]
extern "C" __global__ __launch_bounds__(256) void k_scansums(
    const int* __restrict__ bsum, int* __restrict__ bpre, int* __restrict__ rp, int nb, int n) {
  __shared__ int s[256];
  int t = threadIdx.x;
  int v = (t < nb) ? bsum[t] : 0;
  s[t] = v;
  __syncthreads();
  for (int off = 1; off < 256; off <<= 1) {
    int u = (t >= off) ? s[t - off] : 0;
    __syncthreads();
    s[t] += u;
    __syncthreads();
  }
  if (t < nb) bpre[t] = s[t] - v;          // exclusive prefix
  if (t == 255) rp[n] = s[255];            // grand total
}

// phase 3: per-block local exclusive scan + block offset -> rp, cur
extern "C" __global__ __launch_bounds__(256) void k_scanfin(
    const int* __restrict__ counts, const int* __restrict__ bpre,
    int* __restrict__ rp, int* __restrict__ cur, int n) {
  __shared__ int s[256];
  int t = threadIdx.x;
  int i = blockIdx.x * 256 + t;
  int c = (i < n) ? counts[i] : 0;
  s[t] = c;
  __syncthreads();
  for (int off = 1; off < 256; off <<= 1) {
    int u = (t >= off) ? s[t - off] : 0;
    __syncthreads();
    s[t] += u;
    __syncthreads();
  }
  if (i < n) {
    int e = bpre[blockIdx.x] + s[t] - c;   // exclusive
    rp[i] = e;
    cur[i] = e;
  }
}

extern "C" __global__ void k_scatter(const int* __restrict__ rows, const int* __restrict__ cols,
    const float* __restrict__ vals, int* __restrict__ cur,
    int* __restrict__ scol, float* __restrict__ sval, int n) {
  int i = blockIdx.x * 256 + threadIdx.x;
  if (i < n) {
    int p = atomicAdd(&cur[rows[i]], 1);
    scol[p] = cols[i];
    sval[p] = vals[i];
  }
}

// ---------------- casts ----------------
extern "C" __global__ void k_cast4(const float4* __restrict__ in, ushort4* __restrict__ out, int n4) {
  int i = blockIdx.x * 256 + threadIdx.x;
  if (i < n4) {
    float4 f = in[i];
    ushort4 o; o.x = f2bf(f.x); o.y = f2bf(f.y); o.z = f2bf(f.z); o.w = f2bf(f.w);
    out[i] = o;
  }
}

// W [K][N] row-major (fp32) -> WT [N][K] bf16
extern "C" __global__ void k_transcast(const float* __restrict__ w, unsigned short* __restrict__ wt,
                                       int K, int N) {
  int k = blockIdx.x; int n = threadIdx.x;
  wt[(size_t)n * K + k] = f2bf(w[(size_t)k * N + n]);
}

// ---------------- bf16 MFMA GEMM: C[M][N] = A[M][K] * BT[N][K]^T ----------------
#define BM 128
#define BN 128
#define BK 32

extern "C" __global__ __launch_bounds__(256) void k_gemm(
    const unsigned short* __restrict__ A, const unsigned short* __restrict__ BT,
    float* __restrict__ C, int M, int N, int K) {
  __shared__ __align__(16) unsigned short sA[BM * BK];
  __shared__ __align__(16) unsigned short sB[BN * BK];
  int tid = threadIdx.x;
  int lane = tid & 63, wid = tid >> 6;
  int wm = (wid >> 1) * 64, wn = (wid & 1) * 64;
  int bm = blockIdx.x * BM, bn = blockIdx.y * BN;
  int l15 = lane & 15, lq = lane >> 4;
  f32x4 acc[4][4];
#pragma unroll
  for (int i = 0; i < 4; ++i)
#pragma unroll
    for (int j = 0; j < 4; ++j) acc[i][j] = (f32x4){0.f, 0.f, 0.f, 0.f};

  for (int k0 = 0; k0 < K; k0 += BK) {
#pragma unroll
    for (int i = 0; i < 2; ++i) {
      int u = tid + 256 * i;
      int row = u >> 2, uc = (u & 3) * 8;
      int ga = bm + row; if (ga >= M) ga = M - 1;
      *(float4*)(&sA[row * BK + uc]) = *(const float4*)(A + (size_t)ga * K + k0 + uc);
      int gb = bn + row; if (gb >= N) gb = N - 1;
      *(float4*)(&sB[row * BK + uc]) = *(const float4*)(BT + (size_t)gb * K + k0 + uc);
    }
    __syncthreads();
    bf16x8 af[4], bfr[4];
#pragma unroll
    for (int t = 0; t < 4; ++t) {
      af[t]  = *(const bf16x8*)(&sA[(wm + t * 16 + l15) * BK + lq * 8]);
      bfr[t] = *(const bf16x8*)(&sB[(wn + t * 16 + l15) * BK + lq * 8]);
    }
#pragma unroll
    for (int mt = 0; mt < 4; ++mt)
#pragma unroll
      for (int nt = 0; nt < 4; ++nt)
        acc[mt][nt] = __builtin_amdgcn_mfma_f32_16x16x32_bf16(af[mt], bfr[nt], acc[mt][nt], 0, 0, 0);
    __syncthreads();
  }
#pragma unroll
  for (int mt = 0; mt < 4; ++mt) {
#pragma unroll
    for (int r = 0; r < 4; ++r) {
      int gr = bm + wm + mt * 16 + lq * 4 + r;
      if (gr < M) {
#pragma unroll
        for (int nt = 0; nt < 4; ++nt) {
          int gc = bn + wn + nt * 16 + l15;
          C[(size_t)gr * N + gc] = acc[mt][nt][r];
        }
      }
    }
  }
}

// ---------------- SpMM (CSR row-gather), fused bias+relu ----------------
extern "C" __global__ __launch_bounds__(256) void k_spmm256(
    const int* __restrict__ rp, const int* __restrict__ scol, const float* __restrict__ sval,
    const float* __restrict__ src, const float* __restrict__ bias,
    ushort4* __restrict__ out) {
  int row = blockIdx.x * 4 + (threadIdx.x >> 6);
  int lane = threadIdx.x & 63;
  if (row >= NN) return;
  int e0 = __builtin_amdgcn_readfirstlane(rp[row]);
  int e1 = __builtin_amdgcn_readfirstlane(rp[row + 1]);
  const float4* srcv = (const float4*)src;
  float4 acc = {0.f, 0.f, 0.f, 0.f};
  for (int e = e0; e < e1; ++e) {
    int c = scol[e];
    float v = sval[e];
    float4 g = srcv[(size_t)c * (NH / 4) + lane];
    acc.x = fmaf(v, g.x, acc.x);
    acc.y = fmaf(v, g.y, acc.y);
    acc.z = fmaf(v, g.z, acc.z);
    acc.w = fmaf(v, g.w, acc.w);
  }
  float4 b = ((const float4*)bias)[lane];
  ushort4 o;
  o.x = f2bf(fmaxf(acc.x + b.x, 0.f));
  o.y = f2bf(fmaxf(acc.y + b.y, 0.f));
  o.z = f2bf(fmaxf(acc.z + b.z, 0.f));
  o.w = f2bf(fmaxf(acc.w + b.w, 0.f));
  out[(size_t)row * (NH / 4) + lane] = o;
}

extern "C" __global__ __launch_bounds__(256) void k_spmm128(
    const int* __restrict__ rp, const int* __restrict__ scol, const float* __restrict__ sval,
    const float* __restrict__ src, const float* __restrict__ bias,
    float2* __restrict__ out) {
  int row = blockIdx.x * 4 + (threadIdx.x >> 6);
  int lane = threadIdx.x & 63;
  if (row >= NN) return;
  int e0 = __builtin_amdgcn_readfirstlane(rp[row]);
  int e1 = __builtin_amdgcn_readfirstlane(rp[row + 1]);
  const float2* srcv = (const float2*)src;
  float2 acc = {0.f, 0.f};
  for (int e = e0; e < e1; ++e) {
    int c = scol[e];
    float v = sval[e];
    float2 g = srcv[(size_t)c * (NL / 2) + lane];
    acc.x = fmaf(v, g.x, acc.x);
    acc.y = fmaf(v, g.y, acc.y);
  }
  float2 b = ((const float2*)bias)[lane];
  float2 o;
  o.x = fmaxf(acc.x + b.x, 0.f);
  o.y = fmaxf(acc.y + b.y, 0.f);
  out[(size_t)row * (NL / 2) + lane] = o;
}

// ---------------- launch ----------------
extern "C" void kernel_launch(void* const* d_in, const int* in_sizes, int n_in,
                              void* d_out, int out_size, void* d_ws, size_t ws_size,
                              hipStream_t stream) {
  const float* x   = (const float*)d_in[0];
  const int* erow  = (const int*)d_in[1];
  const int* ecol  = (const int*)d_in[2];
  const float* ev  = (const float*)d_in[3];
  const float* W1  = (const float*)d_in[4];
  const float* b1  = (const float*)d_in[5];
  const float* W2  = (const float*)d_in[6];
  const float* b2  = (const float*)d_in[7];

  char* ws = (char*)d_ws;
  unsigned short* xbf = (unsigned short*)(ws + 0);           // 51,200,000
  float* xw  = (float*)(ws + 51200000);                      // 51,200,000
  unsigned short* hbf = (unsigned short*)(ws + 102400000);   // 25,600,000
  float* hw  = (float*)(ws + 0);                             // 25,600,000 (reuses xbf, dead)
  unsigned short* w1t = (unsigned short*)(ws + 128000000);   // 262,144
  unsigned short* w2t = (unsigned short*)(ws + 128262144);   // 65,536
  int* rp    = (int*)(ws + 128327680);                       // 200,704
  int* cur   = (int*)(ws + 128528384);                       // 200,704
  int* cnt   = (int*)(ws + 128729088);                       // 200,704
  int* bsum  = (int*)(ws + 128929792);                       // 1,024
  int* bpre  = (int*)(ws + 128930816);                       // 1,024
  int* scol  = (int*)(ws + 128931840);                       // 3,200,000
  float* sval = (float*)(ws + 132131840);                    // 3,200,000

  // CSR build
  hipMemsetAsync(cnt, 0, NN * sizeof(int), stream);
  k_hist<<<NE / 256, 256, 0, stream>>>(erow, cnt, NE);
  k_blocksum<<<NB, 256, 0, stream>>>(cnt, bsum, NN);
  k_scansums<<<1, 256, 0, stream>>>(bsum, bpre, rp, NB, NN);
  k_scanfin<<<NB, 256, 0, stream>>>(cnt, bpre, rp, cur, NN);
  k_scatter<<<NE / 256, 256, 0, stream>>>(erow, ecol, ev, cur, scol, sval, NE);

  // layer 1
  k_cast4<<<(NN * NF / 4) / 256, 256, 0, stream>>>((const float4*)x, (ushort4*)xbf, NN * NF / 4);
  k_transcast<<<NF, NH, 0, stream>>>(W1, w1t, NF, NH);
  k_gemm<<<dim3((NN + BM - 1) / BM, NH / BN), 256, 0, stream>>>(xbf, w1t, xw, NN, NH, NF);
  k_spmm256<<<NN / 4, 256, 0, stream>>>(rp, scol, sval, xw, b1, (ushort4*)hbf);

  // layer 2
  k_transcast<<<NH, NL, 0, stream>>>(W2, w2t, NH, NL);
  k_gemm<<<dim3((NN + BM - 1) / BM, NL / BN), 256, 0, stream>>>(hbf, w2t, hw, NN, NL, NH);
  k_spmm128<<<NN / 4, 256, 0, stream>>>(rp, scol, sval, hw, b2, (float2*)d_out);
}

// Round 3
// 434.676 us; speedup vs baseline: 1.3906x; 1.1265x over previous
//
#include <hip/hip_runtime.h>
#include <hip/hip_bf16.h>

// GCN encoder: z = relu(A @ relu(A @ (x@W1) + b1) @ W2 + b2)
// R3: GEMMs write bf16 directly; SpMMs gather bf16 (halves the dominant
// gather traffic -- spmm256 was 112us @ 378MB FETCH, pure BW-bound).

typedef __attribute__((ext_vector_type(8))) short bf16x8;
typedef __attribute__((ext_vector_type(4))) float f32x4;

#define NN 50000
#define NE 800000
#define NF 512
#define NH 256
#define NL 128
#define NB ((NN + 255) / 256)

static __device__ __forceinline__ unsigned short f2bf(float f) {
  union { float f; unsigned int u; } v; v.f = f;
  unsigned int r = v.u + 0x7fffu + ((v.u >> 16) & 1u);   // RNE
  return (unsigned short)(r >> 16);
}
static __device__ __forceinline__ float bf2f(unsigned short u) {
  union { unsigned int u; float f; } v; v.u = (unsigned int)u << 16;
  return v.f;
}

// ---------------- CSR build ----------------
extern "C" __global__ void k_hist(const int* __restrict__ rows, int* __restrict__ counts, int n) {
  int i = blockIdx.x * 256 + threadIdx.x;
  if (i < n) atomicAdd(&counts[rows[i]], 1);
}

extern "C" __global__ __launch_bounds__(256) void k_blocksum(
    const int* __restrict__ counts, int* __restrict__ bsum, int n) {
  __shared__ int s[256];
  int t = threadIdx.x;
  int i = blockIdx.x * 256 + t;
  s[t] = (i < n) ? counts[i] : 0;
  __syncthreads();
  for (int off = 128; off > 0; off >>= 1) {
    if (t < off) s[t] += s[t + off];
    __syncthreads();
  }
  if (t == 0) bsum[blockIdx.x] = s[0];
}

extern "C" __global__ __launch_bounds__(256) void k_scansums(
    const int* __restrict__ bsum, int* __restrict__ bpre, int* __restrict__ rp, int nb, int n) {
  __shared__ int s[256];
  int t = threadIdx.x;
  int v = (t < nb) ? bsum[t] : 0;
  s[t] = v;
  __syncthreads();
  for (int off = 1; off < 256; off <<= 1) {
    int u = (t >= off) ? s[t - off] : 0;
    __syncthreads();
    s[t] += u;
    __syncthreads();
  }
  if (t < nb) bpre[t] = s[t] - v;
  if (t == 255) rp[n] = s[255];
}

extern "C" __global__ __launch_bounds__(256) void k_scanfin(
    const int* __restrict__ counts, const int* __restrict__ bpre,
    int* __restrict__ rp, int* __restrict__ cur, int n) {
  __shared__ int s[256];
  int t = threadIdx.x;
  int i = blockIdx.x * 256 + t;
  int c = (i < n) ? counts[i] : 0;
  s[t] = c;
  __syncthreads();
  for (int off = 1; off < 256; off <<= 1) {
    int u = (t >= off) ? s[t - off] : 0;
    __syncthreads();
    s[t] += u;
    __syncthreads();
  }
  if (i < n) {
    int e = bpre[blockIdx.x] + s[t] - c;
    rp[i] = e;
    cur[i] = e;
  }
}

extern "C" __global__ void k_scatter(const int* __restrict__ rows, const int* __restrict__ cols,
    const float* __restrict__ vals, int* __restrict__ cur,
    int* __restrict__ scol, float* __restrict__ sval, int n) {
  int i = blockIdx.x * 256 + threadIdx.x;
  if (i < n) {
    int p = atomicAdd(&cur[rows[i]], 1);
    scol[p] = cols[i];
    sval[p] = vals[i];
  }
}

// ---------------- casts ----------------
extern "C" __global__ void k_cast4(const float4* __restrict__ in, ushort4* __restrict__ out, int n4) {
  int i = blockIdx.x * 256 + threadIdx.x;
  if (i < n4) {
    float4 f = in[i];
    ushort4 o; o.x = f2bf(f.x); o.y = f2bf(f.y); o.z = f2bf(f.z); o.w = f2bf(f.w);
    out[i] = o;
  }
}

extern "C" __global__ void k_transcast(const float* __restrict__ w, unsigned short* __restrict__ wt,
                                       int K, int N) {
  int k = blockIdx.x; int n = threadIdx.x;
  wt[(size_t)n * K + k] = f2bf(w[(size_t)k * N + n]);
}

// ---------------- bf16 MFMA GEMM: C[M][N] = A[M][K] * BT[N][K]^T, bf16 out ----------------
#define BM 128
#define BN 128
#define BK 32

extern "C" __global__ __launch_bounds__(256) void k_gemm(
    const unsigned short* __restrict__ A, const unsigned short* __restrict__ BT,
    unsigned short* __restrict__ C, int M, int N, int K) {
  __shared__ __align__(16) unsigned short sA[BM * BK];
  __shared__ __align__(16) unsigned short sB[BN * BK];
  int tid = threadIdx.x;
  int lane = tid & 63, wid = tid >> 6;
  int wm = (wid >> 1) * 64, wn = (wid & 1) * 64;
  int bm = blockIdx.x * BM, bn = blockIdx.y * BN;
  int l15 = lane & 15, lq = lane >> 4;
  f32x4 acc[4][4];
#pragma unroll
  for (int i = 0; i < 4; ++i)
#pragma unroll
    for (int j = 0; j < 4; ++j) acc[i][j] = (f32x4){0.f, 0.f, 0.f, 0.f};

  for (int k0 = 0; k0 < K; k0 += BK) {
#pragma unroll
    for (int i = 0; i < 2; ++i) {
      int u = tid + 256 * i;
      int row = u >> 2, uc = (u & 3) * 8;
      int ga = bm + row; if (ga >= M) ga = M - 1;
      *(float4*)(&sA[row * BK + uc]) = *(const float4*)(A + (size_t)ga * K + k0 + uc);
      int gb = bn + row; if (gb >= N) gb = N - 1;
      *(float4*)(&sB[row * BK + uc]) = *(const float4*)(BT + (size_t)gb * K + k0 + uc);
    }
    __syncthreads();
    bf16x8 af[4], bfr[4];
#pragma unroll
    for (int t = 0; t < 4; ++t) {
      af[t]  = *(const bf16x8*)(&sA[(wm + t * 16 + l15) * BK + lq * 8]);
      bfr[t] = *(const bf16x8*)(&sB[(wn + t * 16 + l15) * BK + lq * 8]);
    }
#pragma unroll
    for (int mt = 0; mt < 4; ++mt)
#pragma unroll
      for (int nt = 0; nt < 4; ++nt)
        acc[mt][nt] = __builtin_amdgcn_mfma_f32_16x16x32_bf16(af[mt], bfr[nt], acc[mt][nt], 0, 0, 0);
    __syncthreads();
  }
#pragma unroll
  for (int mt = 0; mt < 4; ++mt) {
#pragma unroll
    for (int r = 0; r < 4; ++r) {
      int gr = bm + wm + mt * 16 + lq * 4 + r;
      if (gr < M) {
#pragma unroll
        for (int nt = 0; nt < 4; ++nt) {
          int gc = bn + wn + nt * 16 + l15;
          C[(size_t)gr * N + gc] = f2bf(acc[mt][nt][r]);
        }
      }
    }
  }
}

// ---------------- SpMM (CSR row-gather), bf16 src, fused bias+relu ----------------
// one wave per row, 256 feats: lane owns 4 bf16 (8B gather)
extern "C" __global__ __launch_bounds__(256) void k_spmm256(
    const int* __restrict__ rp, const int* __restrict__ scol, const float* __restrict__ sval,
    const unsigned short* __restrict__ src, const float* __restrict__ bias,
    ushort4* __restrict__ out) {
  int row = blockIdx.x * 4 + (threadIdx.x >> 6);
  int lane = threadIdx.x & 63;
  if (row >= NN) return;
  int e0 = __builtin_amdgcn_readfirstlane(rp[row]);
  int e1 = __builtin_amdgcn_readfirstlane(rp[row + 1]);
  const ushort4* srcv = (const ushort4*)src;
  float4 acc = {0.f, 0.f, 0.f, 0.f};
  for (int e = e0; e < e1; ++e) {
    int c = scol[e];
    float v = sval[e];
    ushort4 g = srcv[(size_t)c * (NH / 4) + lane];
    acc.x = fmaf(v, bf2f(g.x), acc.x);
    acc.y = fmaf(v, bf2f(g.y), acc.y);
    acc.z = fmaf(v, bf2f(g.z), acc.z);
    acc.w = fmaf(v, bf2f(g.w), acc.w);
  }
  float4 b = ((const float4*)bias)[lane];
  ushort4 o;
  o.x = f2bf(fmaxf(acc.x + b.x, 0.f));
  o.y = f2bf(fmaxf(acc.y + b.y, 0.f));
  o.z = f2bf(fmaxf(acc.z + b.z, 0.f));
  o.w = f2bf(fmaxf(acc.w + b.w, 0.f));
  out[(size_t)row * (NH / 4) + lane] = o;
}

// one wave per row, 128 feats: lane owns 2 bf16 (4B gather); fp32 final out
extern "C" __global__ __launch_bounds__(256) void k_spmm128(
    const int* __restrict__ rp, const int* __restrict__ scol, const float* __restrict__ sval,
    const unsigned short* __restrict__ src, const float* __restrict__ bias,
    float2* __restrict__ out) {
  int row = blockIdx.x * 4 + (threadIdx.x >> 6);
  int lane = threadIdx.x & 63;
  if (row >= NN) return;
  int e0 = __builtin_amdgcn_readfirstlane(rp[row]);
  int e1 = __builtin_amdgcn_readfirstlane(rp[row + 1]);
  const ushort2* srcv = (const ushort2*)src;
  float2 acc = {0.f, 0.f};
  for (int e = e0; e < e1; ++e) {
    int c = scol[e];
    float v = sval[e];
    ushort2 g = srcv[(size_t)c * (NL / 2) + lane];
    acc.x = fmaf(v, bf2f(g.x), acc.x);
    acc.y = fmaf(v, bf2f(g.y), acc.y);
  }
  float2 b = ((const float2*)bias)[lane];
  float2 o;
  o.x = fmaxf(acc.x + b.x, 0.f);
  o.y = fmaxf(acc.y + b.y, 0.f);
  out[(size_t)row * (NL / 2) + lane] = o;
}

// ---------------- launch ----------------
extern "C" void kernel_launch(void* const* d_in, const int* in_sizes, int n_in,
                              void* d_out, int out_size, void* d_ws, size_t ws_size,
                              hipStream_t stream) {
  const float* x   = (const float*)d_in[0];
  const int* erow  = (const int*)d_in[1];
  const int* ecol  = (const int*)d_in[2];
  const float* ev  = (const float*)d_in[3];
  const float* W1  = (const float*)d_in[4];
  const float* b1  = (const float*)d_in[5];
  const float* W2  = (const float*)d_in[6];
  const float* b2  = (const float*)d_in[7];

  char* ws = (char*)d_ws;
  unsigned short* xbf = (unsigned short*)(ws + 0);           // 51,200,000 (x bf16)
  unsigned short* xwb = (unsigned short*)(ws + 51200000);    // 25,600,000 (x@W1 bf16)
  unsigned short* hbf = (unsigned short*)(ws + 76800000);    // 25,600,000 (h bf16)
  unsigned short* hwb = (unsigned short*)(ws + 102400000);   // 12,800,000 (h@W2 bf16)
  unsigned short* w1t = (unsigned short*)(ws + 115200000);   // 262,144
  unsigned short* w2t = (unsigned short*)(ws + 115462144);   // 65,536
  int* rp    = (int*)(ws + 115527680);                       // 200,704
  int* cur   = (int*)(ws + 115728384);                       // 200,704
  int* cnt   = (int*)(ws + 115929088);                       // 200,704
  int* bsum  = (int*)(ws + 116129792);                       // 1,024
  int* bpre  = (int*)(ws + 116130816);                       // 1,024
  int* scol  = (int*)(ws + 116131840);                       // 3,200,000
  float* sval = (float*)(ws + 119331840);                    // 3,200,000

  // CSR build
  hipMemsetAsync(cnt, 0, NN * sizeof(int), stream);
  k_hist<<<NE / 256, 256, 0, stream>>>(erow, cnt, NE);
  k_blocksum<<<NB, 256, 0, stream>>>(cnt, bsum, NN);
  k_scansums<<<1, 256, 0, stream>>>(bsum, bpre, rp, NB, NN);
  k_scanfin<<<NB, 256, 0, stream>>>(cnt, bpre, rp, cur, NN);
  k_scatter<<<NE / 256, 256, 0, stream>>>(erow, ecol, ev, cur, scol, sval, NE);

  // layer 1
  k_cast4<<<(NN * NF / 4) / 256, 256, 0, stream>>>((const float4*)x, (ushort4*)xbf, NN * NF / 4);
  k_transcast<<<NF, NH, 0, stream>>>(W1, w1t, NF, NH);
  k_gemm<<<dim3((NN + BM - 1) / BM, NH / BN), 256, 0, stream>>>(xbf, w1t, xwb, NN, NH, NF);
  k_spmm256<<<NN / 4, 256, 0, stream>>>(rp, scol, sval, xwb, b1, (ushort4*)hbf);

  // layer 2
  k_transcast<<<NH, NL, 0, stream>>>(W2, w2t, NH, NL);
  k_gemm<<<dim3((NN + BM - 1) / BM, NL / BN), 256, 0, stream>>>(hbf, w2t, hwb, NN, NL, NH);
  k_spmm128<<<NN / 4, 256, 0, stream>>>(rp, scol, sval, hwb, b2, (float2*)d_out);
}

// Round 4
// 397.594 us; speedup vs baseline: 1.5203x; 1.0933x over previous
//
#include <hip/hip_runtime.h>
#include <hip/hip_bf16.h>

// GCN encoder: z = relu(A @ relu(A @ (x@W1) + b1) @ W2 + b2)
// R4: spmm unroll-by-4 (4 gathers in flight), int2-packed edges (halves edge
// stream + scatter transactions), GEMM staging via global_load_lds width=16.

typedef __attribute__((ext_vector_type(8))) short bf16x8;
typedef __attribute__((ext_vector_type(4))) float f32x4;

#define NN 50000
#define NE 800000
#define NF 512
#define NH 256
#define NL 128
#define NB ((NN + 255) / 256)

static __device__ __forceinline__ unsigned short f2bf(float f) {
  union { float f; unsigned int u; } v; v.f = f;
  unsigned int r = v.u + 0x7fffu + ((v.u >> 16) & 1u);   // RNE
  return (unsigned short)(r >> 16);
}
static __device__ __forceinline__ float bf2f(unsigned short u) {
  union { unsigned int u; float f; } v; v.u = (unsigned int)u << 16;
  return v.f;
}

// async global->LDS, 16B per lane. LDS dest must be wave-uniform base + lane*16.
static __device__ __forceinline__ void gll16(const void* g, void* l) {
  __builtin_amdgcn_global_load_lds(
      (const __attribute__((address_space(1))) void*)g,
      (__attribute__((address_space(3))) void*)l, 16, 0, 0);
}

// ---------------- CSR build ----------------
extern "C" __global__ void k_hist(const int* __restrict__ rows, int* __restrict__ counts, int n) {
  int i = blockIdx.x * 256 + threadIdx.x;
  if (i < n) atomicAdd(&counts[rows[i]], 1);
}

extern "C" __global__ __launch_bounds__(256) void k_blocksum(
    const int* __restrict__ counts, int* __restrict__ bsum, int n) {
  __shared__ int s[256];
  int t = threadIdx.x;
  int i = blockIdx.x * 256 + t;
  s[t] = (i < n) ? counts[i] : 0;
  __syncthreads();
  for (int off = 128; off > 0; off >>= 1) {
    if (t < off) s[t] += s[t + off];
    __syncthreads();
  }
  if (t == 0) bsum[blockIdx.x] = s[0];
}

extern "C" __global__ __launch_bounds__(256) void k_scansums(
    const int* __restrict__ bsum, int* __restrict__ bpre, int* __restrict__ rp, int nb, int n) {
  __shared__ int s[256];
  int t = threadIdx.x;
  int v = (t < nb) ? bsum[t] : 0;
  s[t] = v;
  __syncthreads();
  for (int off = 1; off < 256; off <<= 1) {
    int u = (t >= off) ? s[t - off] : 0;
    __syncthreads();
    s[t] += u;
    __syncthreads();
  }
  if (t < nb) bpre[t] = s[t] - v;
  if (t == 255) rp[n] = s[255];
}

extern "C" __global__ __launch_bounds__(256) void k_scanfin(
    const int* __restrict__ counts, const int* __restrict__ bpre,
    int* __restrict__ rp, int* __restrict__ cur, int n) {
  __shared__ int s[256];
  int t = threadIdx.x;
  int i = blockIdx.x * 256 + t;
  int c = (i < n) ? counts[i] : 0;
  s[t] = c;
  __syncthreads();
  for (int off = 1; off < 256; off <<= 1) {
    int u = (t >= off) ? s[t - off] : 0;
    __syncthreads();
    s[t] += u;
    __syncthreads();
  }
  if (i < n) {
    int e = bpre[blockIdx.x] + s[t] - c;
    rp[i] = e;
    cur[i] = e;
  }
}

extern "C" __global__ void k_scatter(const int* __restrict__ rows, const int* __restrict__ cols,
    const float* __restrict__ vals, int* __restrict__ cur, int2* __restrict__ ep, int n) {
  int i = blockIdx.x * 256 + threadIdx.x;
  if (i < n) {
    int p = atomicAdd(&cur[rows[i]], 1);
    int2 e; e.x = cols[i]; e.y = __float_as_int(vals[i]);
    ep[p] = e;
  }
}

// ---------------- casts ----------------
extern "C" __global__ void k_cast4(const float4* __restrict__ in, ushort4* __restrict__ out, int n4) {
  int i = blockIdx.x * 256 + threadIdx.x;
  if (i < n4) {
    float4 f = in[i];
    ushort4 o; o.x = f2bf(f.x); o.y = f2bf(f.y); o.z = f2bf(f.z); o.w = f2bf(f.w);
    out[i] = o;
  }
}

extern "C" __global__ void k_transcast(const float* __restrict__ w, unsigned short* __restrict__ wt,
                                       int K, int N) {
  int k = blockIdx.x; int n = threadIdx.x;
  wt[(size_t)n * K + k] = f2bf(w[(size_t)k * N + n]);
}

// ---------------- bf16 MFMA GEMM: C[M][N] = A[M][K] * BT[N][K]^T, bf16 out ----------------
#define BM 128
#define BN 128
#define BK 32

extern "C" __global__ __launch_bounds__(256) void k_gemm(
    const unsigned short* __restrict__ A, const unsigned short* __restrict__ BT,
    unsigned short* __restrict__ C, int M, int N, int K) {
  __shared__ __align__(16) unsigned short sA[BM * BK];
  __shared__ __align__(16) unsigned short sB[BN * BK];
  int tid = threadIdx.x;
  int lane = tid & 63, wid = tid >> 6;
  int wm = (wid >> 1) * 64, wn = (wid & 1) * 64;
  int bm = blockIdx.x * BM, bn = blockIdx.y * BN;
  int l15 = lane & 15, lq = lane >> 4;
  f32x4 acc[4][4];
#pragma unroll
  for (int i = 0; i < 4; ++i)
#pragma unroll
    for (int j = 0; j < 4; ++j) acc[i][j] = (f32x4){0.f, 0.f, 0.f, 0.f};

  for (int k0 = 0; k0 < K; k0 += BK) {
    // async staging: unit u = tid + 256*i -> LDS byte offset u*16 (wave-uniform + lane*16)
#pragma unroll
    for (int i = 0; i < 2; ++i) {
      int u = tid + 256 * i;
      int row = u >> 2, uc = (u & 3) * 8;
      int ga = bm + row; if (ga >= M) ga = M - 1;
      gll16(A + (size_t)ga * K + k0 + uc, &sA[row * BK + uc]);
      int gb = bn + row; if (gb >= N) gb = N - 1;
      gll16(BT + (size_t)gb * K + k0 + uc, &sB[row * BK + uc]);
    }
    __syncthreads();
    bf16x8 af[4], bfr[4];
#pragma unroll
    for (int t = 0; t < 4; ++t) {
      af[t]  = *(const bf16x8*)(&sA[(wm + t * 16 + l15) * BK + lq * 8]);
      bfr[t] = *(const bf16x8*)(&sB[(wn + t * 16 + l15) * BK + lq * 8]);
    }
#pragma unroll
    for (int mt = 0; mt < 4; ++mt)
#pragma unroll
      for (int nt = 0; nt < 4; ++nt)
        acc[mt][nt] = __builtin_amdgcn_mfma_f32_16x16x32_bf16(af[mt], bfr[nt], acc[mt][nt], 0, 0, 0);
    __syncthreads();
  }
#pragma unroll
  for (int mt = 0; mt < 4; ++mt) {
#pragma unroll
    for (int r = 0; r < 4; ++r) {
      int gr = bm + wm + mt * 16 + lq * 4 + r;
      if (gr < M) {
#pragma unroll
        for (int nt = 0; nt < 4; ++nt) {
          int gc = bn + wn + nt * 16 + l15;
          C[(size_t)gr * N + gc] = f2bf(acc[mt][nt][r]);
        }
      }
    }
  }
}

// ---------------- SpMM (CSR row-gather), bf16 src, unroll-4, fused bias+relu ----------------
extern "C" __global__ __launch_bounds__(256) void k_spmm256(
    const int* __restrict__ rp, const int2* __restrict__ ep,
    const unsigned short* __restrict__ src, const float* __restrict__ bias,
    ushort4* __restrict__ out) {
  int row = blockIdx.x * 4 + (threadIdx.x >> 6);
  int lane = threadIdx.x & 63;
  if (row >= NN) return;
  int e0 = __builtin_amdgcn_readfirstlane(rp[row]);
  int e1 = __builtin_amdgcn_readfirstlane(rp[row + 1]);
  const ushort4* srcv = (const ushort4*)src;
  float4 acc = {0.f, 0.f, 0.f, 0.f};
  int e = e0;
  for (; e + 4 <= e1; e += 4) {
    int2 p0 = ep[e], p1 = ep[e + 1], p2 = ep[e + 2], p3 = ep[e + 3];
    ushort4 g0 = srcv[(size_t)p0.x * (NH / 4) + lane];
    ushort4 g1 = srcv[(size_t)p1.x * (NH / 4) + lane];
    ushort4 g2 = srcv[(size_t)p2.x * (NH / 4) + lane];
    ushort4 g3 = srcv[(size_t)p3.x * (NH / 4) + lane];
    float v0 = __int_as_float(p0.y), v1 = __int_as_float(p1.y);
    float v2 = __int_as_float(p2.y), v3 = __int_as_float(p3.y);
    acc.x = fmaf(v0, bf2f(g0.x), acc.x); acc.y = fmaf(v0, bf2f(g0.y), acc.y);
    acc.z = fmaf(v0, bf2f(g0.z), acc.z); acc.w = fmaf(v0, bf2f(g0.w), acc.w);
    acc.x = fmaf(v1, bf2f(g1.x), acc.x); acc.y = fmaf(v1, bf2f(g1.y), acc.y);
    acc.z = fmaf(v1, bf2f(g1.z), acc.z); acc.w = fmaf(v1, bf2f(g1.w), acc.w);
    acc.x = fmaf(v2, bf2f(g2.x), acc.x); acc.y = fmaf(v2, bf2f(g2.y), acc.y);
    acc.z = fmaf(v2, bf2f(g2.z), acc.z); acc.w = fmaf(v2, bf2f(g2.w), acc.w);
    acc.x = fmaf(v3, bf2f(g3.x), acc.x); acc.y = fmaf(v3, bf2f(g3.y), acc.y);
    acc.z = fmaf(v3, bf2f(g3.z), acc.z); acc.w = fmaf(v3, bf2f(g3.w), acc.w);
  }
  for (; e < e1; ++e) {
    int2 p = ep[e];
    float v = __int_as_float(p.y);
    ushort4 g = srcv[(size_t)p.x * (NH / 4) + lane];
    acc.x = fmaf(v, bf2f(g.x), acc.x); acc.y = fmaf(v, bf2f(g.y), acc.y);
    acc.z = fmaf(v, bf2f(g.z), acc.z); acc.w = fmaf(v, bf2f(g.w), acc.w);
  }
  float4 b = ((const float4*)bias)[lane];
  ushort4 o;
  o.x = f2bf(fmaxf(acc.x + b.x, 0.f));
  o.y = f2bf(fmaxf(acc.y + b.y, 0.f));
  o.z = f2bf(fmaxf(acc.z + b.z, 0.f));
  o.w = f2bf(fmaxf(acc.w + b.w, 0.f));
  out[(size_t)row * (NH / 4) + lane] = o;
}

extern "C" __global__ __launch_bounds__(256) void k_spmm128(
    const int* __restrict__ rp, const int2* __restrict__ ep,
    const unsigned short* __restrict__ src, const float* __restrict__ bias,
    float2* __restrict__ out) {
  int row = blockIdx.x * 4 + (threadIdx.x >> 6);
  int lane = threadIdx.x & 63;
  if (row >= NN) return;
  int e0 = __builtin_amdgcn_readfirstlane(rp[row]);
  int e1 = __builtin_amdgcn_readfirstlane(rp[row + 1]);
  const ushort2* srcv = (const ushort2*)src;
  float2 acc = {0.f, 0.f};
  int e = e0;
  for (; e + 4 <= e1; e += 4) {
    int2 p0 = ep[e], p1 = ep[e + 1], p2 = ep[e + 2], p3 = ep[e + 3];
    ushort2 g0 = srcv[(size_t)p0.x * (NL / 2) + lane];
    ushort2 g1 = srcv[(size_t)p1.x * (NL / 2) + lane];
    ushort2 g2 = srcv[(size_t)p2.x * (NL / 2) + lane];
    ushort2 g3 = srcv[(size_t)p3.x * (NL / 2) + lane];
    float v0 = __int_as_float(p0.y), v1 = __int_as_float(p1.y);
    float v2 = __int_as_float(p2.y), v3 = __int_as_float(p3.y);
    acc.x = fmaf(v0, bf2f(g0.x), acc.x); acc.y = fmaf(v0, bf2f(g0.y), acc.y);
    acc.x = fmaf(v1, bf2f(g1.x), acc.x); acc.y = fmaf(v1, bf2f(g1.y), acc.y);
    acc.x = fmaf(v2, bf2f(g2.x), acc.x); acc.y = fmaf(v2, bf2f(g2.y), acc.y);
    acc.x = fmaf(v3, bf2f(g3.x), acc.x); acc.y = fmaf(v3, bf2f(g3.y), acc.y);
  }
  for (; e < e1; ++e) {
    int2 p = ep[e];
    float v = __int_as_float(p.y);
    ushort2 g = srcv[(size_t)p.x * (NL / 2) + lane];
    acc.x = fmaf(v, bf2f(g.x), acc.x); acc.y = fmaf(v, bf2f(g.y), acc.y);
  }
  float2 b = ((const float2*)bias)[lane];
  float2 o;
  o.x = fmaxf(acc.x + b.x, 0.f);
  o.y = fmaxf(acc.y + b.y, 0.f);
  out[(size_t)row * (NL / 2) + lane] = o;
}

// ---------------- launch ----------------
extern "C" void kernel_launch(void* const* d_in, const int* in_sizes, int n_in,
                              void* d_out, int out_size, void* d_ws, size_t ws_size,
                              hipStream_t stream) {
  const float* x   = (const float*)d_in[0];
  const int* erow  = (const int*)d_in[1];
  const int* ecol  = (const int*)d_in[2];
  const float* ev  = (const float*)d_in[3];
  const float* W1  = (const float*)d_in[4];
  const float* b1  = (const float*)d_in[5];
  const float* W2  = (const float*)d_in[6];
  const float* b2  = (const float*)d_in[7];

  char* ws = (char*)d_ws;
  unsigned short* xbf = (unsigned short*)(ws + 0);           // 51,200,000 (x bf16)
  unsigned short* xwb = (unsigned short*)(ws + 51200000);    // 25,600,000 (x@W1 bf16)
  unsigned short* hbf = (unsigned short*)(ws + 76800000);    // 25,600,000 (h bf16)
  unsigned short* hwb = (unsigned short*)(ws + 102400000);   // 12,800,000 (h@W2 bf16)
  unsigned short* w1t = (unsigned short*)(ws + 115200000);   // 262,144
  unsigned short* w2t = (unsigned short*)(ws + 115462144);   // 65,536
  int* rp    = (int*)(ws + 115527680);                       // 200,704
  int* cur   = (int*)(ws + 115728384);                       // 200,704
  int* cnt   = (int*)(ws + 115929088);                       // 200,704
  int* bsum  = (int*)(ws + 116129792);                       // 1,024
  int* bpre  = (int*)(ws + 116130816);                       // 1,024
  int2* ep   = (int2*)(ws + 116131840);                      // 6,400,000

  // CSR build
  hipMemsetAsync(cnt, 0, NN * sizeof(int), stream);
  k_hist<<<NE / 256, 256, 0, stream>>>(erow, cnt, NE);
  k_blocksum<<<NB, 256, 0, stream>>>(cnt, bsum, NN);
  k_scansums<<<1, 256, 0, stream>>>(bsum, bpre, rp, NB, NN);
  k_scanfin<<<NB, 256, 0, stream>>>(cnt, bpre, rp, cur, NN);
  k_scatter<<<NE / 256, 256, 0, stream>>>(erow, ecol, ev, cur, ep, NE);

  // layer 1
  k_cast4<<<(NN * NF / 4) / 256, 256, 0, stream>>>((const float4*)x, (ushort4*)xbf, NN * NF / 4);
  k_transcast<<<NF, NH, 0, stream>>>(W1, w1t, NF, NH);
  k_gemm<<<dim3((NN + BM - 1) / BM, NH / BN), 256, 0, stream>>>(xbf, w1t, xwb, NN, NH, NF);
  k_spmm256<<<NN / 4, 256, 0, stream>>>(rp, ep, xwb, b1, (ushort4*)hbf);

  // layer 2
  k_transcast<<<NH, NL, 0, stream>>>(W2, w2t, NH, NL);
  k_gemm<<<dim3((NN + BM - 1) / BM, NL / BN), 256, 0, stream>>>(hbf, w2t, hwb, NN, NL, NH);
  k_spmm128<<<NN / 4, 256, 0, stream>>>(rp, ep, hwb, b2, (float2*)d_out);
}

// Round 5
// 376.975 us; speedup vs baseline: 1.6035x; 1.0547x over previous
//
#include <hip/hip_runtime.h>
#include <hip/hip_bf16.h>

// GCN encoder: z = relu(A @ relu(A @ (x@W1) + b1) @ W2 + b2)
// R5: cast fused into gemm1 A-staging (fp32 x read directly, -100MB traffic),
// BK=64 (half the barriers), gemm2 BM=64 (grid 391->782 fixes tail),
// spmm unroll-8 (8 gathers in flight).

typedef __attribute__((ext_vector_type(8))) short bf16x8;
typedef __attribute__((ext_vector_type(4))) float f32x4;

#define NN 50000
#define NE 800000
#define NF 512
#define NH 256
#define NL 128
#define NB ((NN + 255) / 256)

static __device__ __forceinline__ unsigned short f2bf(float f) {
  union { float f; unsigned int u; } v; v.f = f;
  unsigned int r = v.u + 0x7fffu + ((v.u >> 16) & 1u);   // RNE
  return (unsigned short)(r >> 16);
}
static __device__ __forceinline__ float bf2f(unsigned short u) {
  union { unsigned int u; float f; } v; v.u = (unsigned int)u << 16;
  return v.f;
}

// async global->LDS, 16B/lane; LDS dest must be wave-uniform base + lane*16.
static __device__ __forceinline__ void gll16(const void* g, void* l) {
  __builtin_amdgcn_global_load_lds(
      (const __attribute__((address_space(1))) void*)g,
      (__attribute__((address_space(3))) void*)l, 16, 0, 0);
}

// ---------------- CSR build ----------------
extern "C" __global__ void k_hist(const int* __restrict__ rows, int* __restrict__ counts, int n) {
  int i = blockIdx.x * 256 + threadIdx.x;
  if (i < n) atomicAdd(&counts[rows[i]], 1);
}

extern "C" __global__ __launch_bounds__(256) void k_blocksum(
    const int* __restrict__ counts, int* __restrict__ bsum, int n) {
  __shared__ int s[256];
  int t = threadIdx.x;
  int i = blockIdx.x * 256 + t;
  s[t] = (i < n) ? counts[i] : 0;
  __syncthreads();
  for (int off = 128; off > 0; off >>= 1) {
    if (t < off) s[t] += s[t + off];
    __syncthreads();
  }
  if (t == 0) bsum[blockIdx.x] = s[0];
}

extern "C" __global__ __launch_bounds__(256) void k_scansums(
    const int* __restrict__ bsum, int* __restrict__ bpre, int* __restrict__ rp, int nb, int n) {
  __shared__ int s[256];
  int t = threadIdx.x;
  int v = (t < nb) ? bsum[t] : 0;
  s[t] = v;
  __syncthreads();
  for (int off = 1; off < 256; off <<= 1) {
    int u = (t >= off) ? s[t - off] : 0;
    __syncthreads();
    s[t] += u;
    __syncthreads();
  }
  if (t < nb) bpre[t] = s[t] - v;
  if (t == 255) rp[n] = s[255];
}

extern "C" __global__ __launch_bounds__(256) void k_scanfin(
    const int* __restrict__ counts, const int* __restrict__ bpre,
    int* __restrict__ rp, int* __restrict__ cur, int n) {
  __shared__ int s[256];
  int t = threadIdx.x;
  int i = blockIdx.x * 256 + t;
  int c = (i < n) ? counts[i] : 0;
  s[t] = c;
  __syncthreads();
  for (int off = 1; off < 256; off <<= 1) {
    int u = (t >= off) ? s[t - off] : 0;
    __syncthreads();
    s[t] += u;
    __syncthreads();
  }
  if (i < n) {
    int e = bpre[blockIdx.x] + s[t] - c;
    rp[i] = e;
    cur[i] = e;
  }
}

extern "C" __global__ void k_scatter(const int* __restrict__ rows, const int* __restrict__ cols,
    const float* __restrict__ vals, int* __restrict__ cur, int2* __restrict__ ep, int n) {
  int i = blockIdx.x * 256 + threadIdx.x;
  if (i < n) {
    int p = atomicAdd(&cur[rows[i]], 1);
    int2 e; e.x = cols[i]; e.y = __float_as_int(vals[i]);
    ep[p] = e;
  }
}

// ---------------- weight transpose-cast: W [K][N] fp32 -> WT [N][K] bf16 ----------------
extern "C" __global__ void k_transcast(const float* __restrict__ w, unsigned short* __restrict__ wt,
                                       int K, int N) {
  int k = blockIdx.x; int n = threadIdx.x;
  wt[(size_t)n * K + k] = f2bf(w[(size_t)k * N + n]);
}

// ---------------- GEMM1: C[NN][256] = x[NN][512](fp32) * W1T[256][512]^T, bf16 out ----------------
// BM=128 BN=128 BK=64; fp32 A staged via register convert; bf16 B via global_load_lds.
extern "C" __global__ __launch_bounds__(256) void k_gemm1(
    const float* __restrict__ A, const unsigned short* __restrict__ BT,
    unsigned short* __restrict__ C) {
  __shared__ __align__(16) unsigned short sA[128 * 64];
  __shared__ __align__(16) unsigned short sB[128 * 64];
  int tid = threadIdx.x;
  int lane = tid & 63, wid = tid >> 6;
  int wm = (wid >> 1) * 64, wn = (wid & 1) * 64;
  int bm = blockIdx.x * 128, bn = blockIdx.y * 128;
  int l15 = lane & 15, lq = lane >> 4;
  f32x4 acc[4][4];
#pragma unroll
  for (int i = 0; i < 4; ++i)
#pragma unroll
    for (int j = 0; j < 4; ++j) acc[i][j] = (f32x4){0.f, 0.f, 0.f, 0.f};

  for (int k0 = 0; k0 < NF; k0 += 64) {
    // A: 128x64 fp32 -> bf16. 2048 float4 units / 256 thr = 8 per thread.
#pragma unroll
    for (int j = 0; j < 8; ++j) {
      int u = tid + 256 * j;
      int row = u >> 4, c4 = (u & 15) * 4;
      int ga = bm + row; if (ga >= NN) ga = NN - 1;
      float4 f = *(const float4*)(A + (size_t)ga * NF + k0 + c4);
      ushort4 o; o.x = f2bf(f.x); o.y = f2bf(f.y); o.z = f2bf(f.z); o.w = f2bf(f.w);
      *(ushort4*)(&sA[row * 64 + c4]) = o;
    }
    // B: 128x64 bf16 = 1024 16B units / 256 thr = 4 per thread (LDS off = u*16: ok for gll)
#pragma unroll
    for (int j = 0; j < 4; ++j) {
      int u = tid + 256 * j;
      int row = u >> 3, c8 = (u & 7) * 8;
      gll16(BT + (size_t)(bn + row) * NF + k0 + c8, &sB[row * 64 + c8]);
    }
    __syncthreads();
#pragma unroll
    for (int ks = 0; ks < 64; ks += 32) {
      bf16x8 af[4], bfr[4];
#pragma unroll
      for (int t = 0; t < 4; ++t) {
        af[t]  = *(const bf16x8*)(&sA[(wm + t * 16 + l15) * 64 + ks + lq * 8]);
        bfr[t] = *(const bf16x8*)(&sB[(wn + t * 16 + l15) * 64 + ks + lq * 8]);
      }
#pragma unroll
      for (int mt = 0; mt < 4; ++mt)
#pragma unroll
        for (int nt = 0; nt < 4; ++nt)
          acc[mt][nt] = __builtin_amdgcn_mfma_f32_16x16x32_bf16(af[mt], bfr[nt], acc[mt][nt], 0, 0, 0);
    }
    __syncthreads();
  }
#pragma unroll
  for (int mt = 0; mt < 4; ++mt) {
#pragma unroll
    for (int r = 0; r < 4; ++r) {
      int gr = bm + wm + mt * 16 + lq * 4 + r;
      if (gr < NN) {
#pragma unroll
        for (int nt = 0; nt < 4; ++nt) {
          int gc = bn + wn + nt * 16 + l15;
          C[(size_t)gr * NH + gc] = f2bf(acc[mt][nt][r]);
        }
      }
    }
  }
}

// ---------------- GEMM2: C[NN][128] = h[NN][256](bf16) * W2T[128][256]^T, bf16 out ----------------
// BM=64 BN=128 BK=64 (grid 782 for tail); both operands via global_load_lds.
extern "C" __global__ __launch_bounds__(256) void k_gemm2(
    const unsigned short* __restrict__ A, const unsigned short* __restrict__ BT,
    unsigned short* __restrict__ C) {
  __shared__ __align__(16) unsigned short sA[64 * 64];
  __shared__ __align__(16) unsigned short sB[128 * 64];
  int tid = threadIdx.x;
  int lane = tid & 63, wid = tid >> 6;
  int wm = (wid >> 1) * 32, wn = (wid & 1) * 64;
  int bm = blockIdx.x * 64;
  int l15 = lane & 15, lq = lane >> 4;
  f32x4 acc[2][4];
#pragma unroll
  for (int i = 0; i < 2; ++i)
#pragma unroll
    for (int j = 0; j < 4; ++j) acc[i][j] = (f32x4){0.f, 0.f, 0.f, 0.f};

  for (int k0 = 0; k0 < NH; k0 += 64) {
    // A: 64x64 bf16 = 512 16B units / 256 thr = 2 per thread
#pragma unroll
    for (int j = 0; j < 2; ++j) {
      int u = tid + 256 * j;
      int row = u >> 3, c8 = (u & 7) * 8;
      int ga = bm + row; if (ga >= NN) ga = NN - 1;
      gll16(A + (size_t)ga * NH + k0 + c8, &sA[row * 64 + c8]);
    }
    // B: 128x64 bf16 = 4 per thread
#pragma unroll
    for (int j = 0; j < 4; ++j) {
      int u = tid + 256 * j;
      int row = u >> 3, c8 = (u & 7) * 8;
      gll16(BT + (size_t)row * NH + k0 + c8, &sB[row * 64 + c8]);
    }
    __syncthreads();
#pragma unroll
    for (int ks = 0; ks < 64; ks += 32) {
      bf16x8 af[2], bfr[4];
#pragma unroll
      for (int t = 0; t < 2; ++t)
        af[t] = *(const bf16x8*)(&sA[(wm + t * 16 + l15) * 64 + ks + lq * 8]);
#pragma unroll
      for (int t = 0; t < 4; ++t)
        bfr[t] = *(const bf16x8*)(&sB[(wn + t * 16 + l15) * 64 + ks + lq * 8]);
#pragma unroll
      for (int mt = 0; mt < 2; ++mt)
#pragma unroll
        for (int nt = 0; nt < 4; ++nt)
          acc[mt][nt] = __builtin_amdgcn_mfma_f32_16x16x32_bf16(af[mt], bfr[nt], acc[mt][nt], 0, 0, 0);
    }
    __syncthreads();
  }
#pragma unroll
  for (int mt = 0; mt < 2; ++mt) {
#pragma unroll
    for (int r = 0; r < 4; ++r) {
      int gr = bm + wm + mt * 16 + lq * 4 + r;
      if (gr < NN) {
#pragma unroll
        for (int nt = 0; nt < 4; ++nt) {
          int gc = wn + nt * 16 + l15;
          C[(size_t)gr * NL + gc] = f2bf(acc[mt][nt][r]);
        }
      }
    }
  }
}

// ---------------- SpMM (CSR row-gather), bf16 src, unroll-8/4/1, fused bias+relu ----------------
extern "C" __global__ __launch_bounds__(256) void k_spmm256(
    const int* __restrict__ rp, const int2* __restrict__ ep,
    const unsigned short* __restrict__ src, const float* __restrict__ bias,
    ushort4* __restrict__ out) {
  int row = blockIdx.x * 4 + (threadIdx.x >> 6);
  int lane = threadIdx.x & 63;
  if (row >= NN) return;
  int e0 = __builtin_amdgcn_readfirstlane(rp[row]);
  int e1 = __builtin_amdgcn_readfirstlane(rp[row + 1]);
  const ushort4* srcv = (const ushort4*)src;
  float4 acc = {0.f, 0.f, 0.f, 0.f};
  int e = e0;
  for (; e + 8 <= e1; e += 8) {
    int2 p[8]; ushort4 g[8];
#pragma unroll
    for (int j = 0; j < 8; ++j) p[j] = ep[e + j];
#pragma unroll
    for (int j = 0; j < 8; ++j) g[j] = srcv[(size_t)p[j].x * (NH / 4) + lane];
#pragma unroll
    for (int j = 0; j < 8; ++j) {
      float v = __int_as_float(p[j].y);
      acc.x = fmaf(v, bf2f(g[j].x), acc.x); acc.y = fmaf(v, bf2f(g[j].y), acc.y);
      acc.z = fmaf(v, bf2f(g[j].z), acc.z); acc.w = fmaf(v, bf2f(g[j].w), acc.w);
    }
  }
  for (; e + 4 <= e1; e += 4) {
    int2 p[4]; ushort4 g[4];
#pragma unroll
    for (int j = 0; j < 4; ++j) p[j] = ep[e + j];
#pragma unroll
    for (int j = 0; j < 4; ++j) g[j] = srcv[(size_t)p[j].x * (NH / 4) + lane];
#pragma unroll
    for (int j = 0; j < 4; ++j) {
      float v = __int_as_float(p[j].y);
      acc.x = fmaf(v, bf2f(g[j].x), acc.x); acc.y = fmaf(v, bf2f(g[j].y), acc.y);
      acc.z = fmaf(v, bf2f(g[j].z), acc.z); acc.w = fmaf(v, bf2f(g[j].w), acc.w);
    }
  }
  for (; e < e1; ++e) {
    int2 p = ep[e];
    float v = __int_as_float(p.y);
    ushort4 g = srcv[(size_t)p.x * (NH / 4) + lane];
    acc.x = fmaf(v, bf2f(g.x), acc.x); acc.y = fmaf(v, bf2f(g.y), acc.y);
    acc.z = fmaf(v, bf2f(g.z), acc.z); acc.w = fmaf(v, bf2f(g.w), acc.w);
  }
  float4 b = ((const float4*)bias)[lane];
  ushort4 o;
  o.x = f2bf(fmaxf(acc.x + b.x, 0.f));
  o.y = f2bf(fmaxf(acc.y + b.y, 0.f));
  o.z = f2bf(fmaxf(acc.z + b.z, 0.f));
  o.w = f2bf(fmaxf(acc.w + b.w, 0.f));
  out[(size_t)row * (NH / 4) + lane] = o;
}

extern "C" __global__ __launch_bounds__(256) void k_spmm128(
    const int* __restrict__ rp, const int2* __restrict__ ep,
    const unsigned short* __restrict__ src, const float* __restrict__ bias,
    float2* __restrict__ out) {
  int row = blockIdx.x * 4 + (threadIdx.x >> 6);
  int lane = threadIdx.x & 63;
  if (row >= NN) return;
  int e0 = __builtin_amdgcn_readfirstlane(rp[row]);
  int e1 = __builtin_amdgcn_readfirstlane(rp[row + 1]);
  const ushort2* srcv = (const ushort2*)src;
  float2 acc = {0.f, 0.f};
  int e = e0;
  for (; e + 8 <= e1; e += 8) {
    int2 p[8]; ushort2 g[8];
#pragma unroll
    for (int j = 0; j < 8; ++j) p[j] = ep[e + j];
#pragma unroll
    for (int j = 0; j < 8; ++j) g[j] = srcv[(size_t)p[j].x * (NL / 2) + lane];
#pragma unroll
    for (int j = 0; j < 8; ++j) {
      float v = __int_as_float(p[j].y);
      acc.x = fmaf(v, bf2f(g[j].x), acc.x); acc.y = fmaf(v, bf2f(g[j].y), acc.y);
    }
  }
  for (; e + 4 <= e1; e += 4) {
    int2 p[4]; ushort2 g[4];
#pragma unroll
    for (int j = 0; j < 4; ++j) p[j] = ep[e + j];
#pragma unroll
    for (int j = 0; j < 4; ++j) g[j] = srcv[(size_t)p[j].x * (NL / 2) + lane];
#pragma unroll
    for (int j = 0; j < 4; ++j) {
      float v = __int_as_float(p[j].y);
      acc.x = fmaf(v, bf2f(g[j].x), acc.x); acc.y = fmaf(v, bf2f(g[j].y), acc.y);
    }
  }
  for (; e < e1; ++e) {
    int2 p = ep[e];
    float v = __int_as_float(p.y);
    ushort2 g = srcv[(size_t)p.x * (NL / 2) + lane];
    acc.x = fmaf(v, bf2f(g.x), acc.x); acc.y = fmaf(v, bf2f(g.y), acc.y);
  }
  float2 b = ((const float2*)bias)[lane];
  float2 o;
  o.x = fmaxf(acc.x + b.x, 0.f);
  o.y = fmaxf(acc.y + b.y, 0.f);
  out[(size_t)row * (NL / 2) + lane] = o;
}

// ---------------- launch ----------------
extern "C" void kernel_launch(void* const* d_in, const int* in_sizes, int n_in,
                              void* d_out, int out_size, void* d_ws, size_t ws_size,
                              hipStream_t stream) {
  const float* x   = (const float*)d_in[0];
  const int* erow  = (const int*)d_in[1];
  const int* ecol  = (const int*)d_in[2];
  const float* ev  = (const float*)d_in[3];
  const float* W1  = (const float*)d_in[4];
  const float* b1  = (const float*)d_in[5];
  const float* W2  = (const float*)d_in[6];
  const float* b2  = (const float*)d_in[7];

  char* ws = (char*)d_ws;
  unsigned short* xwb = (unsigned short*)(ws + 0);           // 25,600,000 (x@W1 bf16)
  unsigned short* hbf = (unsigned short*)(ws + 25600000);    // 25,600,000 (h bf16)
  unsigned short* hwb = (unsigned short*)(ws + 51200000);    // 12,800,000 (h@W2 bf16)
  unsigned short* w1t = (unsigned short*)(ws + 64000000);    // 262,144
  unsigned short* w2t = (unsigned short*)(ws + 64262144);    // 65,536
  int* rp    = (int*)(ws + 64327680);                        // 200,704
  int* cur   = (int*)(ws + 64528384);                        // 200,704
  int* cnt   = (int*)(ws + 64729088);                        // 200,704
  int* bsum  = (int*)(ws + 64929792);                        // 1,024
  int* bpre  = (int*)(ws + 64930816);                        // 1,024
  int2* ep   = (int2*)(ws + 64931840);                       // 6,400,000

  // CSR build
  hipMemsetAsync(cnt, 0, NN * sizeof(int), stream);
  k_hist<<<NE / 256, 256, 0, stream>>>(erow, cnt, NE);
  k_blocksum<<<NB, 256, 0, stream>>>(cnt, bsum, NN);
  k_scansums<<<1, 256, 0, stream>>>(bsum, bpre, rp, NB, NN);
  k_scanfin<<<NB, 256, 0, stream>>>(cnt, bpre, rp, cur, NN);
  k_scatter<<<NE / 256, 256, 0, stream>>>(erow, ecol, ev, cur, ep, NE);

  // layer 1
  k_transcast<<<NF, NH, 0, stream>>>(W1, w1t, NF, NH);
  k_gemm1<<<dim3((NN + 127) / 128, NH / 128), 256, 0, stream>>>(x, w1t, xwb);
  k_spmm256<<<NN / 4, 256, 0, stream>>>(rp, ep, xwb, b1, (ushort4*)hbf);

  // layer 2
  k_transcast<<<NH, NL, 0, stream>>>(W2, w2t, NH, NL);
  k_gemm2<<<(NN + 63) / 64, 256, 0, stream>>>(hbf, w2t, hwb);
  k_spmm128<<<NN / 4, 256, 0, stream>>>(rp, ep, hwb, b2, (float2*)d_out);
}

// Round 6
// 375.395 us; speedup vs baseline: 1.6102x; 1.0042x over previous
//
#include <hip/hip_runtime.h>
#include <hip/hip_bf16.h>

// GCN encoder: z = relu(A @ relu(A @ (x@W1) + b1) @ W2 + b2)
// R6: XOR-swizzled LDS tiles in the GEMMs. R5's BK=64 made the tile row
// stride == 32 banks -> 16-way ds_read_b128 conflicts (4.8M counter, gemm1
// 63us at MfmaUtil 7.5%). Swizzle: LDS 16B-unit (row,cu) holds global unit
// cu^(row&7); global_load_lds keeps contiguous LDS order by swizzling the
// GLOBAL source address instead (m104/m108 constraint).

typedef __attribute__((ext_vector_type(8))) short bf16x8;
typedef __attribute__((ext_vector_type(8))) unsigned short ushort8;
typedef __attribute__((ext_vector_type(4))) float f32x4;

#define NN 50000
#define NE 800000
#define NF 512
#define NH 256
#define NL 128
#define NB ((NN + 255) / 256)

static __device__ __forceinline__ unsigned short f2bf(float f) {
  union { float f; unsigned int u; } v; v.f = f;
  unsigned int r = v.u + 0x7fffu + ((v.u >> 16) & 1u);   // RNE
  return (unsigned short)(r >> 16);
}
static __device__ __forceinline__ float bf2f(unsigned short u) {
  union { unsigned int u; float f; } v; v.u = (unsigned int)u << 16;
  return v.f;
}

// async global->LDS, 16B/lane; LDS dest must be wave-uniform base + lane*16.
static __device__ __forceinline__ void gll16(const void* g, void* l) {
  __builtin_amdgcn_global_load_lds(
      (const __attribute__((address_space(1))) void*)g,
      (__attribute__((address_space(3))) void*)l, 16, 0, 0);
}

// ---------------- CSR build ----------------
extern "C" __global__ void k_hist(const int* __restrict__ rows, int* __restrict__ counts, int n) {
  int i = blockIdx.x * 256 + threadIdx.x;
  if (i < n) atomicAdd(&counts[rows[i]], 1);
}

extern "C" __global__ __launch_bounds__(256) void k_blocksum(
    const int* __restrict__ counts, int* __restrict__ bsum, int n) {
  __shared__ int s[256];
  int t = threadIdx.x;
  int i = blockIdx.x * 256 + t;
  s[t] = (i < n) ? counts[i] : 0;
  __syncthreads();
  for (int off = 128; off > 0; off >>= 1) {
    if (t < off) s[t] += s[t + off];
    __syncthreads();
  }
  if (t == 0) bsum[blockIdx.x] = s[0];
}

extern "C" __global__ __launch_bounds__(256) void k_scansums(
    const int* __restrict__ bsum, int* __restrict__ bpre, int* __restrict__ rp, int nb, int n) {
  __shared__ int s[256];
  int t = threadIdx.x;
  int v = (t < nb) ? bsum[t] : 0;
  s[t] = v;
  __syncthreads();
  for (int off = 1; off < 256; off <<= 1) {
    int u = (t >= off) ? s[t - off] : 0;
    __syncthreads();
    s[t] += u;
    __syncthreads();
  }
  if (t < nb) bpre[t] = s[t] - v;
  if (t == 255) rp[n] = s[255];
}

extern "C" __global__ __launch_bounds__(256) void k_scanfin(
    const int* __restrict__ counts, const int* __restrict__ bpre,
    int* __restrict__ rp, int* __restrict__ cur, int n) {
  __shared__ int s[256];
  int t = threadIdx.x;
  int i = blockIdx.x * 256 + t;
  int c = (i < n) ? counts[i] : 0;
  s[t] = c;
  __syncthreads();
  for (int off = 1; off < 256; off <<= 1) {
    int u = (t >= off) ? s[t - off] : 0;
    __syncthreads();
    s[t] += u;
    __syncthreads();
  }
  if (i < n) {
    int e = bpre[blockIdx.x] + s[t] - c;
    rp[i] = e;
    cur[i] = e;
  }
}

extern "C" __global__ void k_scatter(const int* __restrict__ rows, const int* __restrict__ cols,
    const float* __restrict__ vals, int* __restrict__ cur, int2* __restrict__ ep, int n) {
  int i = blockIdx.x * 256 + threadIdx.x;
  if (i < n) {
    int p = atomicAdd(&cur[rows[i]], 1);
    int2 e; e.x = cols[i]; e.y = __float_as_int(vals[i]);
    ep[p] = e;
  }
}

// ---------------- weight transpose-cast: W [K][N] fp32 -> WT [N][K] bf16 ----------------
extern "C" __global__ void k_transcast(const float* __restrict__ w, unsigned short* __restrict__ wt,
                                       int K, int N) {
  int k = blockIdx.x; int n = threadIdx.x;
  wt[(size_t)n * K + k] = f2bf(w[(size_t)k * N + n]);
}

// ---------------- GEMM1: C[NN][256] = x[NN][512](fp32) * W1T[256][512]^T, bf16 out ----------------
// BM=128 BN=128 BK=64; fp32 A staged via register convert (swizzled ds_write);
// bf16 B via global_load_lds with swizzled GLOBAL source.
extern "C" __global__ __launch_bounds__(256) void k_gemm1(
    const float* __restrict__ A, const unsigned short* __restrict__ BT,
    unsigned short* __restrict__ C) {
  __shared__ __align__(16) unsigned short sA[128 * 64];
  __shared__ __align__(16) unsigned short sB[128 * 64];
  int tid = threadIdx.x;
  int lane = tid & 63, wid = tid >> 6;
  int wm = (wid >> 1) * 64, wn = (wid & 1) * 64;
  int bm = blockIdx.x * 128, bn = blockIdx.y * 128;
  int l15 = lane & 15, lq = lane >> 4;
  int swzbase = l15 & 7;                  // row&7 for all fragment rows this lane reads
  f32x4 acc[4][4];
#pragma unroll
  for (int i = 0; i < 4; ++i)
#pragma unroll
    for (int j = 0; j < 4; ++j) acc[i][j] = (f32x4){0.f, 0.f, 0.f, 0.f};

  for (int k0 = 0; k0 < NF; k0 += 64) {
    // A: 128x64 tile = 1024 16B-units; 4 units/thread. unit u: row=u>>3, cu=u&7.
    // store global cu at LDS unit cu^(row&7).
#pragma unroll
    for (int j = 0; j < 4; ++j) {
      int u = tid + 256 * j;
      int row = u >> 3, cu = u & 7;
      int ga = bm + row; if (ga >= NN) ga = NN - 1;
      const float* src = A + (size_t)ga * NF + k0 + cu * 8;
      float4 f0 = *(const float4*)src;
      float4 f1 = *(const float4*)(src + 4);
      ushort8 o;
      o[0] = f2bf(f0.x); o[1] = f2bf(f0.y); o[2] = f2bf(f0.z); o[3] = f2bf(f0.w);
      o[4] = f2bf(f1.x); o[5] = f2bf(f1.y); o[6] = f2bf(f1.z); o[7] = f2bf(f1.w);
      *(ushort8*)(&sA[row * 64 + (cu ^ (row & 7)) * 8]) = o;
    }
    // B: 1024 16B-units, 4/thread via gll16. LDS stays contiguous (unit u -> u*16B);
    // lane fetches the global unit that belongs at u: g = (u&7)^(row&7).
#pragma unroll
    for (int j = 0; j < 4; ++j) {
      int u = tid + 256 * j;
      int row = u >> 3, cu = u & 7;
      int g = cu ^ (row & 7);
      gll16(BT + (size_t)(bn + row) * NF + k0 + g * 8, &sB[u * 8]);
    }
    __syncthreads();
#pragma unroll
    for (int ks = 0; ks < 64; ks += 32) {
      bf16x8 af[4], bfr[4];
#pragma unroll
      for (int t = 0; t < 4; ++t) {
        int sz = (((ks >> 3) + lq) ^ swzbase) * 8;
        af[t]  = *(const bf16x8*)(&sA[(wm + t * 16 + l15) * 64 + sz]);
        bfr[t] = *(const bf16x8*)(&sB[(wn + t * 16 + l15) * 64 + sz]);
      }
#pragma unroll
      for (int mt = 0; mt < 4; ++mt)
#pragma unroll
        for (int nt = 0; nt < 4; ++nt)
          acc[mt][nt] = __builtin_amdgcn_mfma_f32_16x16x32_bf16(af[mt], bfr[nt], acc[mt][nt], 0, 0, 0);
    }
    __syncthreads();
  }
#pragma unroll
  for (int mt = 0; mt < 4; ++mt) {
#pragma unroll
    for (int r = 0; r < 4; ++r) {
      int gr = bm + wm + mt * 16 + lq * 4 + r;
      if (gr < NN) {
#pragma unroll
        for (int nt = 0; nt < 4; ++nt) {
          int gc = bn + wn + nt * 16 + l15;
          C[(size_t)gr * NH + gc] = f2bf(acc[mt][nt][r]);
        }
      }
    }
  }
}

// ---------------- GEMM2: C[NN][128] = h[NN][256](bf16) * W2T[128][256]^T, bf16 out ----------------
// BM=64 BN=128 BK=64; both operands via gll16 with swizzled global source.
extern "C" __global__ __launch_bounds__(256) void k_gemm2(
    const unsigned short* __restrict__ A, const unsigned short* __restrict__ BT,
    unsigned short* __restrict__ C) {
  __shared__ __align__(16) unsigned short sA[64 * 64];
  __shared__ __align__(16) unsigned short sB[128 * 64];
  int tid = threadIdx.x;
  int lane = tid & 63, wid = tid >> 6;
  int wm = (wid >> 1) * 32, wn = (wid & 1) * 64;
  int bm = blockIdx.x * 64;
  int l15 = lane & 15, lq = lane >> 4;
  int swzbase = l15 & 7;
  f32x4 acc[2][4];
#pragma unroll
  for (int i = 0; i < 2; ++i)
#pragma unroll
    for (int j = 0; j < 4; ++j) acc[i][j] = (f32x4){0.f, 0.f, 0.f, 0.f};

  for (int k0 = 0; k0 < NH; k0 += 64) {
    // A: 64x64 = 512 units, 2/thread
#pragma unroll
    for (int j = 0; j < 2; ++j) {
      int u = tid + 256 * j;
      int row = u >> 3, cu = u & 7;
      int ga = bm + row; if (ga >= NN) ga = NN - 1;
      int g = cu ^ (row & 7);
      gll16(A + (size_t)ga * NH + k0 + g * 8, &sA[u * 8]);
    }
    // B: 128x64 = 1024 units, 4/thread
#pragma unroll
    for (int j = 0; j < 4; ++j) {
      int u = tid + 256 * j;
      int row = u >> 3, cu = u & 7;
      int g = cu ^ (row & 7);
      gll16(BT + (size_t)row * NH + k0 + g * 8, &sB[u * 8]);
    }
    __syncthreads();
#pragma unroll
    for (int ks = 0; ks < 64; ks += 32) {
      bf16x8 af[2], bfr[4];
#pragma unroll
      for (int t = 0; t < 2; ++t)
        af[t] = *(const bf16x8*)(&sA[(wm + t * 16 + l15) * 64 + (((ks >> 3) + lq) ^ swzbase) * 8]);
#pragma unroll
      for (int t = 0; t < 4; ++t)
        bfr[t] = *(const bf16x8*)(&sB[(wn + t * 16 + l15) * 64 + (((ks >> 3) + lq) ^ swzbase) * 8]);
#pragma unroll
      for (int mt = 0; mt < 2; ++mt)
#pragma unroll
        for (int nt = 0; nt < 4; ++nt)
          acc[mt][nt] = __builtin_amdgcn_mfma_f32_16x16x32_bf16(af[mt], bfr[nt], acc[mt][nt], 0, 0, 0);
    }
    __syncthreads();
  }
#pragma unroll
  for (int mt = 0; mt < 2; ++mt) {
#pragma unroll
    for (int r = 0; r < 4; ++r) {
      int gr = bm + wm + mt * 16 + lq * 4 + r;
      if (gr < NN) {
#pragma unroll
        for (int nt = 0; nt < 4; ++nt) {
          int gc = wn + nt * 16 + l15;
          C[(size_t)gr * NL + gc] = f2bf(acc[mt][nt][r]);
        }
      }
    }
  }
}

// ---------------- SpMM (CSR row-gather), bf16 src, unroll-8/4/1, fused bias+relu ----------------
extern "C" __global__ __launch_bounds__(256) void k_spmm256(
    const int* __restrict__ rp, const int2* __restrict__ ep,
    const unsigned short* __restrict__ src, const float* __restrict__ bias,
    ushort4* __restrict__ out) {
  int row = blockIdx.x * 4 + (threadIdx.x >> 6);
  int lane = threadIdx.x & 63;
  if (row >= NN) return;
  int e0 = __builtin_amdgcn_readfirstlane(rp[row]);
  int e1 = __builtin_amdgcn_readfirstlane(rp[row + 1]);
  const ushort4* srcv = (const ushort4*)src;
  float4 acc = {0.f, 0.f, 0.f, 0.f};
  int e = e0;
  for (; e + 8 <= e1; e += 8) {
    int2 p[8]; ushort4 g[8];
#pragma unroll
    for (int j = 0; j < 8; ++j) p[j] = ep[e + j];
#pragma unroll
    for (int j = 0; j < 8; ++j) g[j] = srcv[(size_t)p[j].x * (NH / 4) + lane];
#pragma unroll
    for (int j = 0; j < 8; ++j) {
      float v = __int_as_float(p[j].y);
      acc.x = fmaf(v, bf2f(g[j].x), acc.x); acc.y = fmaf(v, bf2f(g[j].y), acc.y);
      acc.z = fmaf(v, bf2f(g[j].z), acc.z); acc.w = fmaf(v, bf2f(g[j].w), acc.w);
    }
  }
  for (; e + 4 <= e1; e += 4) {
    int2 p[4]; ushort4 g[4];
#pragma unroll
    for (int j = 0; j < 4; ++j) p[j] = ep[e + j];
#pragma unroll
    for (int j = 0; j < 4; ++j) g[j] = srcv[(size_t)p[j].x * (NH / 4) + lane];
#pragma unroll
    for (int j = 0; j < 4; ++j) {
      float v = __int_as_float(p[j].y);
      acc.x = fmaf(v, bf2f(g[j].x), acc.x); acc.y = fmaf(v, bf2f(g[j].y), acc.y);
      acc.z = fmaf(v, bf2f(g[j].z), acc.z); acc.w = fmaf(v, bf2f(g[j].w), acc.w);
    }
  }
  for (; e < e1; ++e) {
    int2 p = ep[e];
    float v = __int_as_float(p.y);
    ushort4 g = srcv[(size_t)p.x * (NH / 4) + lane];
    acc.x = fmaf(v, bf2f(g.x), acc.x); acc.y = fmaf(v, bf2f(g.y), acc.y);
    acc.z = fmaf(v, bf2f(g.z), acc.z); acc.w = fmaf(v, bf2f(g.w), acc.w);
  }
  float4 b = ((const float4*)bias)[lane];
  ushort4 o;
  o.x = f2bf(fmaxf(acc.x + b.x, 0.f));
  o.y = f2bf(fmaxf(acc.y + b.y, 0.f));
  o.z = f2bf(fmaxf(acc.z + b.z, 0.f));
  o.w = f2bf(fmaxf(acc.w + b.w, 0.f));
  out[(size_t)row * (NH / 4) + lane] = o;
}

extern "C" __global__ __launch_bounds__(256) void k_spmm128(
    const int* __restrict__ rp, const int2* __restrict__ ep,
    const unsigned short* __restrict__ src, const float* __restrict__ bias,
    float2* __restrict__ out) {
  int row = blockIdx.x * 4 + (threadIdx.x >> 6);
  int lane = threadIdx.x & 63;
  if (row >= NN) return;
  int e0 = __builtin_amdgcn_readfirstlane(rp[row]);
  int e1 = __builtin_amdgcn_readfirstlane(rp[row + 1]);
  const ushort2* srcv = (const ushort2*)src;
  float2 acc = {0.f, 0.f};
  int e = e0;
  for (; e + 8 <= e1; e += 8) {
    int2 p[8]; ushort2 g[8];
#pragma unroll
    for (int j = 0; j < 8; ++j) p[j] = ep[e + j];
#pragma unroll
    for (int j = 0; j < 8; ++j) g[j] = srcv[(size_t)p[j].x * (NL / 2) + lane];
#pragma unroll
    for (int j = 0; j < 8; ++j) {
      float v = __int_as_float(p[j].y);
      acc.x = fmaf(v, bf2f(g[j].x), acc.x); acc.y = fmaf(v, bf2f(g[j].y), acc.y);
    }
  }
  for (; e + 4 <= e1; e += 4) {
    int2 p[4]; ushort2 g[4];
#pragma unroll
    for (int j = 0; j < 4; ++j) p[j] = ep[e + j];
#pragma unroll
    for (int j = 0; j < 4; ++j) g[j] = srcv[(size_t)p[j].x * (NL / 2) + lane];
#pragma unroll
    for (int j = 0; j < 4; ++j) {
      float v = __int_as_float(p[j].y);
      acc.x = fmaf(v, bf2f(g[j].x), acc.x); acc.y = fmaf(v, bf2f(g[j].y), acc.y);
    }
  }
  for (; e < e1; ++e) {
    int2 p = ep[e];
    float v = __int_as_float(p.y);
    ushort2 g = srcv[(size_t)p.x * (NL / 2) + lane];
    acc.x = fmaf(v, bf2f(g.x), acc.x); acc.y = fmaf(v, bf2f(g.y), acc.y);
  }
  float2 b = ((const float2*)bias)[lane];
  float2 o;
  o.x = fmaxf(acc.x + b.x, 0.f);
  o.y = fmaxf(acc.y + b.y, 0.f);
  out[(size_t)row * (NL / 2) + lane] = o;
}

// ---------------- launch ----------------
extern "C" void kernel_launch(void* const* d_in, const int* in_sizes, int n_in,
                              void* d_out, int out_size, void* d_ws, size_t ws_size,
                              hipStream_t stream) {
  const float* x   = (const float*)d_in[0];
  const int* erow  = (const int*)d_in[1];
  const int* ecol  = (const int*)d_in[2];
  const float* ev  = (const float*)d_in[3];
  const float* W1  = (const float*)d_in[4];
  const float* b1  = (const float*)d_in[5];
  const float* W2  = (const float*)d_in[6];
  const float* b2  = (const float*)d_in[7];

  char* ws = (char*)d_ws;
  unsigned short* xwb = (unsigned short*)(ws + 0);           // 25,600,000 (x@W1 bf16)
  unsigned short* hbf = (unsigned short*)(ws + 25600000);    // 25,600,000 (h bf16)
  unsigned short* hwb = (unsigned short*)(ws + 51200000);    // 12,800,000 (h@W2 bf16)
  unsigned short* w1t = (unsigned short*)(ws + 64000000);    // 262,144
  unsigned short* w2t = (unsigned short*)(ws + 64262144);    // 65,536
  int* rp    = (int*)(ws + 64327680);                        // 200,704
  int* cur   = (int*)(ws + 64528384);                        // 200,704
  int* cnt   = (int*)(ws + 64729088);                        // 200,704
  int* bsum  = (int*)(ws + 64929792);                        // 1,024
  int* bpre  = (int*)(ws + 64930816);                        // 1,024
  int2* ep   = (int2*)(ws + 64931840);                       // 6,400,000

  // CSR build
  hipMemsetAsync(cnt, 0, NN * sizeof(int), stream);
  k_hist<<<NE / 256, 256, 0, stream>>>(erow, cnt, NE);
  k_blocksum<<<NB, 256, 0, stream>>>(cnt, bsum, NN);
  k_scansums<<<1, 256, 0, stream>>>(bsum, bpre, rp, NB, NN);
  k_scanfin<<<NB, 256, 0, stream>>>(cnt, bpre, rp, cur, NN);
  k_scatter<<<NE / 256, 256, 0, stream>>>(erow, ecol, ev, cur, ep, NE);

  // layer 1
  k_transcast<<<NF, NH, 0, stream>>>(W1, w1t, NF, NH);
  k_gemm1<<<dim3((NN + 127) / 128, NH / 128), 256, 0, stream>>>(x, w1t, xwb);
  k_spmm256<<<NN / 4, 256, 0, stream>>>(rp, ep, xwb, b1, (ushort4*)hbf);

  // layer 2
  k_transcast<<<NH, NL, 0, stream>>>(W2, w2t, NH, NL);
  k_gemm2<<<(NN + 63) / 64, 256, 0, stream>>>(hbf, w2t, hwb);
  k_spmm128<<<NN / 4, 256, 0, stream>>>(rp, ep, hwb, b2, (float2*)d_out);
}